// Round 2
// baseline (210.245 us; speedup 1.0000x reference)
//
#include <hip/hip_runtime.h>
#include <hip/hip_bf16.h>
#include <stdint.h>

typedef __hip_bfloat16 bf16;
typedef __attribute__((ext_vector_type(8))) short short8;   // 8 bf16 = 4 VGPRs (MFMA A/B frag)
typedef __attribute__((ext_vector_type(4))) float floatx4;  // MFMA C/D frag

#define MFMA_BF16(a, b, c) __builtin_amdgcn_mfma_f32_16x16x32_bf16((a), (b), (c), 0, 0, 0)

// Problem constants: B=2, N=2048, C=1024, H=8, D=128, half-window 128.
// qkv workspace layout: [b][n][3*C] with col = which*1024 + h*128 + d
// Vt layout: [b][h][d][n]  (PV B-frags contiguous in key)

// ---------------------------------------------------------------------------
// Dtype sniff: inputs are either fp32 (per reference) or bf16 (if harness
// downcasts). For bf16 N(0,1) data, halfword[2i] is a bf16 with exponent in
// [100,140] (~100% of lanes). For fp32 data, halfword[2i] is the LOW mantissa
// half of a float -> exponent field uniform 0..255 (~16% in band).
// flag = 1 -> bf16 inputs/outputs, 0 -> fp32 inputs/outputs.
// ---------------------------------------------------------------------------
__global__ void sniff_kernel(const uint16_t* __restrict__ x, int* __restrict__ flag)
{
    if (threadIdx.x == 0 && blockIdx.x == 0) {
        int cnt = 0;
        for (int i = 0; i < 64; ++i) {
            const int e = (x[2 * i] >> 7) & 0xFF;
            cnt += (e >= 100 && e <= 140) ? 1 : 0;
        }
        *flag = (cnt >= 32) ? 1 : 0;
    }
}

// src -> bf16 workspace (copy if already bf16, downconvert if fp32)
__global__ void cvt_bf16_kernel(const void* __restrict__ src, bf16* __restrict__ dst,
                                int n, const int* __restrict__ flag)
{
    const int i = blockIdx.x * 256 + threadIdx.x;
    if (i >= n) return;
    if (*flag)
        dst[i] = ((const bf16*)src)[i];
    else
        dst[i] = __float2bfloat16(((const float*)src)[i]);
}

// src -> fp32 workspace (biases; upconvert if bf16)
__global__ void cvt_f32_kernel(const void* __restrict__ src, float* __restrict__ dst,
                               int n, const int* __restrict__ flag)
{
    const int i = blockIdx.x * 256 + threadIdx.x;
    if (i >= n) return;
    if (*flag)
        dst[i] = __bfloat162float(((const bf16*)src)[i]);
    else
        dst[i] = ((const float*)src)[i];
}

// ---------------------------------------------------------------------------
// GEMM: C[m,n] = sum_k A[m,k] * W[n,k] + bias[n]   (x @ W^T + b, W row-major NxK)
// Tile 128x128, BK=32, 256 threads (4 waves in 2x2), 16 MFMA tiles per wave.
// DYN_OUT: output dtype chosen at runtime by *flag (1=bf16, 0=fp32).
// ---------------------------------------------------------------------------
template <bool FUSE_VT, bool DYN_OUT>
__global__ void __launch_bounds__(256, 2)
gemm_bt_kernel(const bf16* __restrict__ A, const bf16* __restrict__ W,
               const float* __restrict__ bias, void* __restrict__ Cout,
               int M, int Nc, int K, bf16* __restrict__ Vt,
               const int* __restrict__ flag)
{
    __shared__ __align__(16) bf16 As[128][40];  // 32 cols + 8 pad
    __shared__ __align__(16) bf16 Bs[128][40];

    const int tid  = threadIdx.x;
    const int lane = tid & 63;
    const int wave = tid >> 6;
    const int quad = lane >> 4;
    const int l16  = lane & 15;
    const int wm   = (wave & 1) * 64;
    const int wn   = (wave >> 1) * 64;
    const int bm   = blockIdx.x * 128;
    const int bn   = blockIdx.y * 128;

    const bool outbf = DYN_OUT ? (*flag != 0) : true;

    // staging: each thread moves 2x16B for A and B per K-step
    const int r0 = tid >> 2;         // rows r0, r0+64
    const int c0 = (tid & 3) * 8;    // col (bf16 elems)

    floatx4 acc[4][4];
#pragma unroll
    for (int i = 0; i < 4; ++i)
#pragma unroll
        for (int j = 0; j < 4; ++j)
#pragma unroll
            for (int r = 0; r < 4; ++r) acc[i][j][r] = 0.0f;

    const bf16* Ag = A + (size_t)(bm + r0) * K + c0;
    const bf16* Wg = W + (size_t)(bn + r0) * K + c0;

    for (int k0 = 0; k0 < K; k0 += 32) {
        *(uint4*)(&As[r0][c0])      = *(const uint4*)(Ag + k0);
        *(uint4*)(&As[r0 + 64][c0]) = *(const uint4*)(Ag + (size_t)64 * K + k0);
        *(uint4*)(&Bs[r0][c0])      = *(const uint4*)(Wg + k0);
        *(uint4*)(&Bs[r0 + 64][c0]) = *(const uint4*)(Wg + (size_t)64 * K + k0);
        __syncthreads();

        short8 af[4], bfr[4];
#pragma unroll
        for (int i = 0; i < 4; ++i)
            af[i] = *(const short8*)(&As[wm + i * 16 + l16][quad * 8]);
#pragma unroll
        for (int j = 0; j < 4; ++j)
            bfr[j] = *(const short8*)(&Bs[wn + j * 16 + l16][quad * 8]);
#pragma unroll
        for (int i = 0; i < 4; ++i)
#pragma unroll
            for (int j = 0; j < 4; ++j)
                acc[i][j] = MFMA_BF16(af[i], bfr[j], acc[i][j]);
        __syncthreads();
    }

    // epilogue: C/D layout row = quad*4+r, col = l16
#pragma unroll
    for (int i = 0; i < 4; ++i) {
#pragma unroll
        for (int j = 0; j < 4; ++j) {
            const int col = bn + wn + j * 16 + l16;
            const float bv = bias[col];
#pragma unroll
            for (int r = 0; r < 4; ++r) {
                const int row = bm + wm + i * 16 + quad * 4 + r;
                const float v = acc[i][j][r] + bv;
                const size_t idx = (size_t)row * Nc + col;
                if (!DYN_OUT || outbf) {
                    ((bf16*)Cout)[idx] = __float2bfloat16(v);
                } else {
                    ((float*)Cout)[idx] = v;
                }
                if (FUSE_VT) {
                    if (col >= 2048) {  // V columns -> also write transposed copy
                        const int hh = (col - 2048) >> 7;
                        const int dd = (col - 2048) & 127;
                        const int bb = row >> 11;     // M = 4096 = B*N
                        const int nn = row & 2047;
                        Vt[(((size_t)bb * 8 + hh) * 128 + dd) * 2048 + nn] =
                            __float2bfloat16(v);
                    }
                }
            }
        }
    }
}

// ---------------------------------------------------------------------------
// Banded flash attention. Block = 256 thr (4 waves). Block handles (b, h, 64
// queries); wave w owns queries q0 = qb*64 + w*16. Block-uniform key-chunk
// loop (32 keys/chunk); band mask handles edges.
// ---------------------------------------------------------------------------
__global__ void __launch_bounds__(256, 2)
attn_kernel(const bf16* __restrict__ qkv, const bf16* __restrict__ Vt,
            bf16* __restrict__ out)
{
    const int tid  = threadIdx.x;
    const int wave = tid >> 6;
    const int lane = tid & 63;
    const int quad = lane >> 4;
    const int l16  = lane & 15;

    const int qb = blockIdx.x & 31;         // 32 query-blocks of 64
    const int h  = (blockIdx.x >> 5) & 7;
    const int b  = blockIdx.x >> 8;

    const int q0 = qb * 64 + wave * 16;

    // Q A-frags: A[m=l16][k=quad*8+j], 4 chunks of K(=d)=32
    short8 qf[4];
    {
        const bf16* Qbase = qkv + (size_t)(b * 2048 + q0 + l16) * 3072 + h * 128 + quad * 8;
#pragma unroll
        for (int d = 0; d < 4; ++d)
            qf[d] = *(const short8*)(Qbase + d * 32);
    }

    floatx4 Oacc[8];  // 8 d-tiles of 16; C-layout rows = quad*4+r (query)
#pragma unroll
    for (int dt = 0; dt < 8; ++dt)
#pragma unroll
        for (int r = 0; r < 4; ++r) Oacc[dt][r] = 0.0f;
    float mrow[4], lrow[4];
#pragma unroll
    for (int r = 0; r < 4; ++r) { mrow[r] = -1e30f; lrow[r] = 0.0f; }

    __shared__ __align__(16) bf16 Plds[2][4][16][40];  // [dbuf][wave][16 q][32 keys + pad]

    int lo = qb * 64 - 127; if (lo < 0) lo = 0; lo &= ~31;
    int hi = qb * 64 + 63 + 127; if (hi > 2047) hi = 2047;

    const bf16* Kb0 = qkv + (size_t)b * 2048 * 3072 + 1024 + h * 128 + quad * 8;
    const bf16* Vb0 = Vt + ((size_t)(b * 8 + h) * 128) * 2048;

    int t = 0;
    for (int key0 = lo; key0 <= hi; key0 += 32, ++t) {
        // ---- S = Q K^T (two 16-key halves) ----
        floatx4 s[2];
#pragma unroll
        for (int half = 0; half < 2; ++half) {
#pragma unroll
            for (int r = 0; r < 4; ++r) s[half][r] = 0.0f;
            const bf16* Kb = Kb0 + (size_t)(key0 + half * 16 + l16) * 3072;
#pragma unroll
            for (int d = 0; d < 4; ++d) {
                short8 kf = *(const short8*)(Kb + d * 32);
                s[half] = MFMA_BF16(qf[d], kf, s[half]);
            }
        }
        // ---- scale + band mask; tile row-max ----
        float tmax[4], tsum[4], p[2][4];
#pragma unroll
        for (int r = 0; r < 4; ++r) {
            const int i = q0 + quad * 4 + r;
#pragma unroll
            for (int half = 0; half < 2; ++half) {
                const int j = key0 + half * 16 + l16;
                float v = s[half][r] * 0.03125f;  // 1/sqrt(C=1024)
                const int dif = i - j;
                if (dif >= 128 || dif <= -128) v = -1e30f;
                s[half][r] = v;
            }
            tmax[r] = fmaxf(s[0][r], s[1][r]);
        }
#pragma unroll
        for (int m = 1; m <= 8; m <<= 1)
#pragma unroll
            for (int r = 0; r < 4; ++r)
                tmax[r] = fmaxf(tmax[r], __shfl_xor(tmax[r], m, 64));
        // ---- online softmax update ----
        float alpha[4];
#pragma unroll
        for (int r = 0; r < 4; ++r) {
            const float mn = fmaxf(mrow[r], tmax[r]);
            alpha[r] = __expf(mrow[r] - mn);
            mrow[r] = mn;
            // guard: fully-masked tile keeps p = 0 even when mn == -1e30
            p[0][r] = (s[0][r] > -1e29f) ? __expf(s[0][r] - mn) : 0.0f;
            p[1][r] = (s[1][r] > -1e29f) ? __expf(s[1][r] - mn) : 0.0f;
            tsum[r] = p[0][r] + p[1][r];
        }
#pragma unroll
        for (int m = 1; m <= 8; m <<= 1)
#pragma unroll
            for (int r = 0; r < 4; ++r)
                tsum[r] += __shfl_xor(tsum[r], m, 64);
#pragma unroll
        for (int r = 0; r < 4; ++r)
            lrow[r] = lrow[r] * alpha[r] + tsum[r];
        // ---- P: C-layout -> LDS (bf16) ----
#pragma unroll
        for (int r = 0; r < 4; ++r) {
            Plds[t & 1][wave][quad * 4 + r][l16]      = __float2bfloat16(p[0][r]);
            Plds[t & 1][wave][quad * 4 + r][16 + l16] = __float2bfloat16(p[1][r]);
        }
        // rescale O while stores land
#pragma unroll
        for (int dt = 0; dt < 8; ++dt)
#pragma unroll
            for (int r = 0; r < 4; ++r) Oacc[dt][r] *= alpha[r];
        __syncthreads();
        // ---- P as A-frag; V B-frags from Vt (contiguous in key) ----
        short8 pf = *(const short8*)(&Plds[t & 1][wave][l16][quad * 8]);
        const bf16* Vb = Vb0 + key0 + quad * 8;
#pragma unroll
        for (int dt = 0; dt < 8; ++dt) {
            short8 vf = *(const short8*)(Vb + (size_t)(dt * 16 + l16) * 2048);
            Oacc[dt] = MFMA_BF16(pf, vf, Oacc[dt]);
        }
    }

    // ---- write O / l ----
#pragma unroll
    for (int dt = 0; dt < 8; ++dt) {
#pragma unroll
        for (int r = 0; r < 4; ++r) {
            const int row = q0 + quad * 4 + r;
            const float v = Oacc[dt][r] / lrow[r];
            out[(size_t)(b * 2048 + row) * 1024 + h * 128 + dt * 16 + l16] = __float2bfloat16(v);
        }
    }
}

// ---------------------------------------------------------------------------
extern "C" void kernel_launch(void* const* d_in, const int* in_sizes, int n_in,
                              void* d_out, int out_size, void* d_ws, size_t ws_size,
                              hipStream_t stream)
{
    (void)in_sizes; (void)n_in; (void)out_size; (void)ws_size;

    const void* x      = d_in[0];  // (2, 2048, 1024)  fp32 or bf16
    const void* w_qkv  = d_in[1];  // (3072, 1024)
    const void* b_qkv  = d_in[2];  // (3072,)
    const void* w_proj = d_in[3];  // (1024, 1024)
    const void* b_proj = d_in[4];  // (1024,)

    char* ws = (char*)d_ws;
    bf16*  qkv      = (bf16*)(ws);                 // 25,165,824 B  [b][n][3C]
    bf16*  Vt       = (bf16*)(ws + 25165824);      //  8,388,608 B  [b][h][d][n]
    bf16*  attn_out = (bf16*)(ws + 33554432);      //  8,388,608 B  (b,n,c)
    bf16*  xb       = (bf16*)(ws + 41943040);      //  8,388,608 B
    bf16*  wqkvb    = (bf16*)(ws + 50331648);      //  6,291,456 B
    bf16*  wprojb   = (bf16*)(ws + 56623104);      //  2,097,152 B
    float* bqf      = (float*)(ws + 58720256);     //     12,288 B
    float* bpf      = (float*)(ws + 58732544);     //      4,096 B
    int*   flag     = (int*)(ws + 58736640);       //          4 B

    dim3 blk(256);

    // 0) detect input dtype (fp32 per reference, bf16 if harness downcast)
    sniff_kernel<<<1, 64, 0, stream>>>((const uint16_t*)x, flag);

    // 1) normalize all inputs: matrices -> bf16 workspace, biases -> fp32
    cvt_bf16_kernel<<<(4194304 + 255) / 256, blk, 0, stream>>>(x, xb, 4194304, flag);
    cvt_bf16_kernel<<<(3145728 + 255) / 256, blk, 0, stream>>>(w_qkv, wqkvb, 3145728, flag);
    cvt_bf16_kernel<<<(1048576 + 255) / 256, blk, 0, stream>>>(w_proj, wprojb, 1048576, flag);
    cvt_f32_kernel<<<(3072 + 255) / 256, blk, 0, stream>>>(b_qkv, bqf, 3072, flag);
    cvt_f32_kernel<<<(1024 + 255) / 256, blk, 0, stream>>>(b_proj, bpf, 1024, flag);

    // 2) qkv = x @ w_qkv^T + b_qkv  (+ fused transposed-V write), bf16 out
    gemm_bt_kernel<true, false><<<dim3(32, 24), blk, 0, stream>>>(
        xb, wqkvb, bqf, qkv, 4096, 3072, 1024, Vt, flag);

    // 3) banded flash attention
    attn_kernel<<<dim3(512), blk, 0, stream>>>(qkv, Vt, attn_out);

    // 4) out = attn @ w_proj^T + b_proj, output dtype per flag
    gemm_bt_kernel<false, true><<<dim3(32, 8), blk, 0, stream>>>(
        attn_out, wprojb, bpf, d_out, 4096, 1024, 1024, nullptr, flag);
}

// Round 3
// 192.723 us; speedup vs baseline: 1.0909x; 1.0909x over previous
//
#include <hip/hip_runtime.h>
#include <hip/hip_bf16.h>
#include <stdint.h>

typedef __hip_bfloat16 bf16;
typedef __attribute__((ext_vector_type(8))) short short8;   // 8 bf16 = 4 VGPRs (MFMA A/B frag)
typedef __attribute__((ext_vector_type(4))) float floatx4;  // MFMA C/D frag

#define MFMA_BF16(a, b, c) __builtin_amdgcn_mfma_f32_16x16x32_bf16((a), (b), (c), 0, 0, 0)

// Problem constants: B=2, N=2048, C=1024, H=8, D=128, half-window 128.
// qkv workspace layout: [b][n][3*C] with col = which*1024 + h*128 + d
// Vt layout: [b][h][d][n]  (PV B-frags contiguous in key)

// ---------------------------------------------------------------------------
// async global->LDS 16B copy: LDS dst must be wave-uniform (lane i lands at
// dst + i*16 bytes); gsrc is per-lane. [m97-verified pattern]
// ---------------------------------------------------------------------------
__device__ __forceinline__ void gl_lds16(const bf16* gsrc, bf16* lds_dst)
{
    __builtin_amdgcn_global_load_lds(
        (const __attribute__((address_space(1))) uint32_t*)(uintptr_t)gsrc,
        (__attribute__((address_space(3))) uint32_t*)(uintptr_t)lds_dst,
        16, 0, 0);
}

// ---------------------------------------------------------------------------
// Dtype sniff (inlined, per block): bf16 N(0,1) halfword[2i] has exponent in
// [100,140] ~always; fp32 low-mantissa halfwords hit that band ~16%.
// ---------------------------------------------------------------------------
__device__ __forceinline__ int sniff_bf16(const uint16_t* __restrict__ x)
{
    int cnt = 0;
#pragma unroll
    for (int i = 0; i < 64; ++i) {
        const int e = (x[2 * i] >> 7) & 0xFF;
        cnt += (e >= 100 && e <= 140) ? 1 : 0;
    }
    return (cnt >= 32) ? 1 : 0;
}

// ---------------------------------------------------------------------------
// One fused conversion kernel: x / w_qkv / w_proj -> bf16 (vectorized 8/thr),
// biases -> fp32. Grid = 4100 blocks x 256.
//   blocks [0,2048)    : x      (4,194,304 elems)
//   blocks [2048,3584) : w_qkv  (3,145,728)
//   blocks [3584,4096) : w_proj (1,048,576)
//   blocks 4096..4098  : b_qkv  (3072, 1024/blk)
//   block  4099        : b_proj (1024)
// ---------------------------------------------------------------------------
__global__ void __launch_bounds__(256)
cvt_all_kernel(const void* __restrict__ x, const void* __restrict__ wq,
               const void* __restrict__ wp, const void* __restrict__ bq,
               const void* __restrict__ bp,
               bf16* __restrict__ xb, bf16* __restrict__ wqb,
               bf16* __restrict__ wpb, float* __restrict__ bqf,
               float* __restrict__ bpf)
{
    __shared__ int sflag;
    if (threadIdx.x == 0) sflag = sniff_bf16((const uint16_t*)x);
    __syncthreads();
    const bool isbf = (sflag != 0);

    const int blk = blockIdx.x;
    if (blk < 4096) {
        const void* src; bf16* dst; int base;
        if (blk < 2048)      { src = x;  dst = xb;  base = blk << 11; }
        else if (blk < 3584) { src = wq; dst = wqb; base = (blk - 2048) << 11; }
        else                 { src = wp; dst = wpb; base = (blk - 3584) << 11; }
        const int i = base + (int)threadIdx.x * 8;
        if (isbf) {
            *(uint4*)(dst + i) = *(const uint4*)((const bf16*)src + i);
        } else {
            const float4 f0 = *(const float4*)((const float*)src + i);
            const float4 f1 = *(const float4*)((const float*)src + i + 4);
            bf16 o[8];
            o[0] = __float2bfloat16(f0.x); o[1] = __float2bfloat16(f0.y);
            o[2] = __float2bfloat16(f0.z); o[3] = __float2bfloat16(f0.w);
            o[4] = __float2bfloat16(f1.x); o[5] = __float2bfloat16(f1.y);
            o[6] = __float2bfloat16(f1.z); o[7] = __float2bfloat16(f1.w);
            *(uint4*)(dst + i) = *(uint4*)o;
        }
    } else {
        const void* src; float* dst; int base, n;
        if (blk < 4099) { src = bq; dst = bqf; base = (blk - 4096) * 1024; n = 3072; }
        else            { src = bp; dst = bpf; base = 0;                   n = 1024; }
        const int i0 = base + (int)threadIdx.x * 4;
#pragma unroll
        for (int k = 0; k < 4; ++k) {
            const int idx = i0 + k;
            if (idx < n)
                dst[idx] = isbf ? __bfloat162float(((const bf16*)src)[idx])
                                : ((const float*)src)[idx];
        }
    }
}

// ---------------------------------------------------------------------------
// GEMM: C[m,n] = sum_k A[m,k] * W[n,k] + bias[n]   (x @ W^T + b, W row-major)
// 128x128 tile, BK=32, 4 waves (2x2), m97-style global_load_lds staging.
// DYN_OUT: output dtype by runtime sniff (1=bf16, 0=fp32).
// ---------------------------------------------------------------------------
template <bool FUSE_VT, bool DYN_OUT>
__global__ void __launch_bounds__(256, 2)
gemm_bt_kernel(const bf16* __restrict__ A, const bf16* __restrict__ W,
               const float* __restrict__ bias, void* __restrict__ Cout,
               int M, int Nc, int K, bf16* __restrict__ Vt,
               const uint16_t* __restrict__ sniffsrc)
{
    __shared__ __align__(16) bf16 As[128][32];  // unpadded: global_load_lds layout
    __shared__ __align__(16) bf16 Bs[128][32];
    __shared__ int sflag;

    const int tid  = threadIdx.x;
    const int lane = tid & 63;
    const int wave = tid >> 6;
    const int quad = lane >> 4;
    const int l16  = lane & 15;
    const int wm   = (wave & 1) * 64;
    const int wn   = (wave >> 1) * 64;
    const int bm   = blockIdx.x * 128;
    const int bn   = blockIdx.y * 128;

    if (DYN_OUT && tid == 0) sflag = sniff_bf16(sniffsrc);

    // staging geometry: chunk c = (wave*2+t)*64 + lane; row = c>>2, col16 = c&3
    const int grow = wave * 32 + (lane >> 2);   // row for t=0 (t=1 adds 16)
    const int gcol = (lane & 3) * 8;            // element col
    const bf16* Ag = A + (size_t)(bm + grow) * K + gcol;
    const bf16* Wg = W + (size_t)(bn + grow) * K + gcol;
    bf16* AsD0 = &As[0][0] + (wave * 2 + 0) * 512;  // wave-uniform LDS bases
    bf16* AsD1 = &As[0][0] + (wave * 2 + 1) * 512;
    bf16* BsD0 = &Bs[0][0] + (wave * 2 + 0) * 512;
    bf16* BsD1 = &Bs[0][0] + (wave * 2 + 1) * 512;

    floatx4 acc[4][4];
#pragma unroll
    for (int i = 0; i < 4; ++i)
#pragma unroll
        for (int j = 0; j < 4; ++j)
#pragma unroll
            for (int r = 0; r < 4; ++r) acc[i][j][r] = 0.0f;

    for (int k0 = 0; k0 < K; k0 += 32) {
        gl_lds16(Ag + k0,                    AsD0);
        gl_lds16(Ag + (size_t)16 * K + k0,   AsD1);
        gl_lds16(Wg + k0,                    BsD0);
        gl_lds16(Wg + (size_t)16 * K + k0,   BsD1);
        __syncthreads();

        short8 af[4], bfr[4];
#pragma unroll
        for (int i = 0; i < 4; ++i)
            af[i] = *(const short8*)(&As[wm + i * 16 + l16][quad * 8]);
#pragma unroll
        for (int j = 0; j < 4; ++j)
            bfr[j] = *(const short8*)(&Bs[wn + j * 16 + l16][quad * 8]);
#pragma unroll
        for (int i = 0; i < 4; ++i)
#pragma unroll
            for (int j = 0; j < 4; ++j)
                acc[i][j] = MFMA_BF16(af[i], bfr[j], acc[i][j]);
        __syncthreads();
    }

    const bool outbf = DYN_OUT ? (sflag != 0) : true;

    // epilogue: C/D layout row = quad*4+r, col = l16
#pragma unroll
    for (int i = 0; i < 4; ++i) {
#pragma unroll
        for (int j = 0; j < 4; ++j) {
            const int col = bn + wn + j * 16 + l16;
            const float bv = bias[col];
#pragma unroll
            for (int r = 0; r < 4; ++r) {
                const int row = bm + wm + i * 16 + quad * 4 + r;
                const float v = acc[i][j][r] + bv;
                const size_t idx = (size_t)row * Nc + col;
                if (!DYN_OUT || outbf) {
                    ((bf16*)Cout)[idx] = __float2bfloat16(v);
                } else {
                    ((float*)Cout)[idx] = v;
                }
                if (FUSE_VT) {
                    if (col >= 2048) {  // V columns -> transposed copy
                        const int hh = (col - 2048) >> 7;
                        const int dd = (col - 2048) & 127;
                        const int bb = row >> 11;     // M = 4096 = B*N
                        const int nn = row & 2047;
                        Vt[(((size_t)bb * 8 + hh) * 128 + dd) * 2048 + nn] =
                            __float2bfloat16(v);
                    }
                }
            }
        }
    }
}

// ---------------------------------------------------------------------------
// Banded flash attention. Block = 4 waves; block handles (b, h, 64 queries);
// wave w owns queries q0 = qb*64 + w*16. Block-uniform 32-key chunk loop.
// ---------------------------------------------------------------------------
__global__ void __launch_bounds__(256, 2)
attn_kernel(const bf16* __restrict__ qkv, const bf16* __restrict__ Vt,
            bf16* __restrict__ out)
{
    const int tid  = threadIdx.x;
    const int wave = tid >> 6;
    const int lane = tid & 63;
    const int quad = lane >> 4;
    const int l16  = lane & 15;

    const int qb = blockIdx.x & 31;         // 32 query-blocks of 64
    const int h  = (blockIdx.x >> 5) & 7;
    const int b  = blockIdx.x >> 8;

    const int q0 = qb * 64 + wave * 16;

    short8 qf[4];
    {
        const bf16* Qbase = qkv + (size_t)(b * 2048 + q0 + l16) * 3072 + h * 128 + quad * 8;
#pragma unroll
        for (int d = 0; d < 4; ++d)
            qf[d] = *(const short8*)(Qbase + d * 32);
    }

    floatx4 Oacc[8];
#pragma unroll
    for (int dt = 0; dt < 8; ++dt)
#pragma unroll
        for (int r = 0; r < 4; ++r) Oacc[dt][r] = 0.0f;
    float mrow[4], lrow[4];
#pragma unroll
    for (int r = 0; r < 4; ++r) { mrow[r] = -1e30f; lrow[r] = 0.0f; }

    __shared__ __align__(16) bf16 Plds[2][4][16][40];

    int lo = qb * 64 - 127; if (lo < 0) lo = 0; lo &= ~31;
    int hi = qb * 64 + 63 + 127; if (hi > 2047) hi = 2047;

    const bf16* Kb0 = qkv + (size_t)b * 2048 * 3072 + 1024 + h * 128 + quad * 8;
    const bf16* Vb0 = Vt + ((size_t)(b * 8 + h) * 128) * 2048;

    int t = 0;
    for (int key0 = lo; key0 <= hi; key0 += 32, ++t) {
        floatx4 s[2];
#pragma unroll
        for (int half = 0; half < 2; ++half) {
#pragma unroll
            for (int r = 0; r < 4; ++r) s[half][r] = 0.0f;
            const bf16* Kb = Kb0 + (size_t)(key0 + half * 16 + l16) * 3072;
#pragma unroll
            for (int d = 0; d < 4; ++d) {
                short8 kf = *(const short8*)(Kb + d * 32);
                s[half] = MFMA_BF16(qf[d], kf, s[half]);
            }
        }
        float tmax[4], tsum[4], p[2][4];
#pragma unroll
        for (int r = 0; r < 4; ++r) {
            const int i = q0 + quad * 4 + r;
#pragma unroll
            for (int half = 0; half < 2; ++half) {
                const int j = key0 + half * 16 + l16;
                float v = s[half][r] * 0.03125f;  // 1/sqrt(1024)
                const int dif = i - j;
                if (dif >= 128 || dif <= -128) v = -1e30f;
                s[half][r] = v;
            }
            tmax[r] = fmaxf(s[0][r], s[1][r]);
        }
#pragma unroll
        for (int m = 1; m <= 8; m <<= 1)
#pragma unroll
            for (int r = 0; r < 4; ++r)
                tmax[r] = fmaxf(tmax[r], __shfl_xor(tmax[r], m, 64));
        float alpha[4];
#pragma unroll
        for (int r = 0; r < 4; ++r) {
            const float mn = fmaxf(mrow[r], tmax[r]);
            alpha[r] = __expf(mrow[r] - mn);
            mrow[r] = mn;
            p[0][r] = (s[0][r] > -1e29f) ? __expf(s[0][r] - mn) : 0.0f;
            p[1][r] = (s[1][r] > -1e29f) ? __expf(s[1][r] - mn) : 0.0f;
            tsum[r] = p[0][r] + p[1][r];
        }
#pragma unroll
        for (int m = 1; m <= 8; m <<= 1)
#pragma unroll
            for (int r = 0; r < 4; ++r)
                tsum[r] += __shfl_xor(tsum[r], m, 64);
#pragma unroll
        for (int r = 0; r < 4; ++r)
            lrow[r] = lrow[r] * alpha[r] + tsum[r];
#pragma unroll
        for (int r = 0; r < 4; ++r) {
            Plds[t & 1][wave][quad * 4 + r][l16]      = __float2bfloat16(p[0][r]);
            Plds[t & 1][wave][quad * 4 + r][16 + l16] = __float2bfloat16(p[1][r]);
        }
#pragma unroll
        for (int dt = 0; dt < 8; ++dt)
#pragma unroll
            for (int r = 0; r < 4; ++r) Oacc[dt][r] *= alpha[r];
        __syncthreads();
        short8 pf = *(const short8*)(&Plds[t & 1][wave][l16][quad * 8]);
        const bf16* Vb = Vb0 + key0 + quad * 8;
#pragma unroll
        for (int dt = 0; dt < 8; ++dt) {
            short8 vf = *(const short8*)(Vb + (size_t)(dt * 16 + l16) * 2048);
            Oacc[dt] = MFMA_BF16(pf, vf, Oacc[dt]);
        }
    }

#pragma unroll
    for (int dt = 0; dt < 8; ++dt) {
#pragma unroll
        for (int r = 0; r < 4; ++r) {
            const int row = q0 + quad * 4 + r;
            const float v = Oacc[dt][r] / lrow[r];
            out[(size_t)(b * 2048 + row) * 1024 + h * 128 + dt * 16 + l16] = __float2bfloat16(v);
        }
    }
}

// ---------------------------------------------------------------------------
extern "C" void kernel_launch(void* const* d_in, const int* in_sizes, int n_in,
                              void* d_out, int out_size, void* d_ws, size_t ws_size,
                              hipStream_t stream)
{
    (void)in_sizes; (void)n_in; (void)out_size; (void)ws_size;

    const void* x      = d_in[0];  // (2, 2048, 1024)  fp32 (or bf16 — sniffed)
    const void* w_qkv  = d_in[1];  // (3072, 1024)
    const void* b_qkv  = d_in[2];  // (3072,)
    const void* w_proj = d_in[3];  // (1024, 1024)
    const void* b_proj = d_in[4];  // (1024,)

    char* ws = (char*)d_ws;
    bf16*  qkv      = (bf16*)(ws);                 // 25,165,824 B  [b][n][3C]
    bf16*  Vt       = (bf16*)(ws + 25165824);      //  8,388,608 B  [b][h][d][n]
    bf16*  attn_out = (bf16*)(ws + 33554432);      //  8,388,608 B  (b,n,c)
    bf16*  xb       = (bf16*)(ws + 41943040);      //  8,388,608 B
    bf16*  wqkvb    = (bf16*)(ws + 50331648);      //  6,291,456 B
    bf16*  wprojb   = (bf16*)(ws + 56623104);      //  2,097,152 B
    float* bqf      = (float*)(ws + 58720256);     //     12,288 B
    float* bpf      = (float*)(ws + 58732544);     //      4,096 B

    dim3 blk(256);

    // 1) one fused input-normalization kernel (sniff inlined per block)
    cvt_all_kernel<<<dim3(4100), blk, 0, stream>>>(
        x, w_qkv, w_proj, b_qkv, b_proj, xb, wqkvb, wprojb, bqf, bpf);

    // 2) qkv = x @ w_qkv^T + b_qkv  (+ fused transposed-V write)
    gemm_bt_kernel<true, false><<<dim3(32, 24), blk, 0, stream>>>(
        xb, wqkvb, bqf, qkv, 4096, 3072, 1024, Vt, (const uint16_t*)x);

    // 3) banded flash attention
    attn_kernel<<<dim3(512), blk, 0, stream>>>(qkv, Vt, attn_out);

    // 4) out = attn @ w_proj^T + b_proj, output dtype per sniff
    gemm_bt_kernel<false, true><<<dim3(32, 8), blk, 0, stream>>>(
        attn_out, wprojb, bpf, d_out, 4096, 1024, 1024, nullptr, (const uint16_t*)x);
}